// Round 4
// baseline (306.206 us; speedup 1.0000x reference)
//
#include <hip/hip_runtime.h>
#include <hip/hip_bf16.h>

// MonarchOutProjection: out[t][r*32+q] = sum_p R[q][r][p] * sum_m L[p][q][m] * x[t][m*32+p]
// Round 6: r4 structure (clean traffic: FETCH 70MB / WRITE 139MB), one variable
// changed: co-residency. r2/r4/r5 all ~87-95us with every pipe <15% busy and only
// 2-3 blocks/CU resident -> latency-chain bound, concurrency is the divisor.
//  - __launch_bounds__(256,5): VGPR cap 102 (r4 demand 84), LDS 32KB -> 5 blocks/CU,
//    20 waves/CU (2.5x r4's measured 8).
//  - x prefetch split 2x8 float4 to keep peak live regs ~95 < 102 (no spill).
//  - otherwise r4 verbatim: single 32KB LDS buffer, batched reads + lgkm-only
//    barriers (never drain vmcnt), sequential la->ra weight residency,
//    swizzle el ^ (t<<2) (<=4-way banks, b64-safe).

typedef __attribute__((ext_vector_type(8))) short short8;
typedef __attribute__((ext_vector_type(4))) float floatx4;

__device__ __forceinline__ unsigned int pack2bf(float a, float b) {
    __hip_bfloat162 h = __float22bfloat162_rn(float2{a, b});  // packed cvt
    return *(unsigned int*)&h;
}
__device__ __forceinline__ float bf2f(unsigned int u16) {
    return __uint_as_float(u16 << 16);
}

// Barrier with LDS-only drain: do NOT drain vmcnt (keeps global loads in flight).
__device__ __forceinline__ void block_sync() {
    asm volatile("s_waitcnt lgkmcnt(0)" ::: "memory");
    __builtin_amdgcn_s_barrier();
    asm volatile("" ::: "memory");
}

// Lb[(p*2+qt)*64 + lane] (short8) = L[p][q=qt*16+(lane&15)][m=(lane>>4)*8 .. +8] as bf16.
// Same for Rb. 8192 threads, one short8 each. (unchanged)
__global__ void prep_weights(const float* __restrict__ L, const float* __restrict__ R,
                             unsigned short* __restrict__ Lb, unsigned short* __restrict__ Rb) {
    const int t = blockIdx.x * 256 + threadIdx.x;          // 0..8191
    const float* src        = (t < 4096) ? L : R;
    unsigned short* dst     = (t < 4096) ? Lb : Rb;
    const int i    = t & 4095;                             // (p*2+qt)*64 + lane
    const int lane = i & 63;
    const int pq   = i >> 6;
    const int p    = pq >> 1;
    const int qt   = pq & 1;
    const int q    = qt * 16 + (lane & 15);
    const int m0   = (lane >> 4) * 8;
    const float* s = src + (p * 32 + q) * 32 + m0;
    uint4 o;
    o.x = pack2bf(s[0], s[1]);
    o.y = pack2bf(s[2], s[3]);
    o.z = pack2bf(s[4], s[5]);
    o.w = pack2bf(s[6], s[7]);
    *(uint4*)(dst + (size_t)i * 8) = o;
}

__global__ __launch_bounds__(256, 5)
void monarch_kernel(const float* __restrict__ x,
                    const unsigned short* __restrict__ Lb,
                    const unsigned short* __restrict__ Rb,
                    float* __restrict__ out) {
    // One buffer, three logical lives: x (channel layout m*32+p), y1 ([p*32+q]),
    // y2 ([r*32+q] == output channel layout). Element el of row t lives at
    // el ^ (t<<2): XOR bits 2..5 -> 16-bank spread, b64 alignment preserved.
    __shared__ __align__(16) unsigned short buf[16][1024];   // 32 KiB -> 5 blocks/CU

    const int tid  = threadIdx.x;
    const int w    = tid >> 6;
    const int lane = tid & 63;
    const int tl   = lane & 15;       // token row / MFMA col
    const int quad = lane >> 4;
    const int c    = tid * 4;         // stage-in / dump channel base
    const long tok0 = (long)blockIdx.x * 16;

    // ---------- phase 0: x loads in two batches of 8 (peak live ~95 VGPR) ----------
    {
        float4 xv[8];
        #pragma unroll
        for (int t = 0; t < 8; ++t)
            xv[t] = *(const float4*)(x + (tok0 + t) * 1024 + c);
        #pragma unroll
        for (int t = 0; t < 8; ++t) {
            const unsigned long long v =
                ((unsigned long long)pack2bf(xv[t].z, xv[t].w) << 32) | pack2bf(xv[t].x, xv[t].y);
            *(unsigned long long*)&buf[t][c ^ (t << 2)] = v;
        }
    }
    {
        float4 xv[8];
        #pragma unroll
        for (int t = 0; t < 8; ++t)
            xv[t] = *(const float4*)(x + (tok0 + 8 + t) * 1024 + c);
        #pragma unroll
        for (int t = 0; t < 8; ++t) {
            const int tt = 8 + t;
            const unsigned long long v =
                ((unsigned long long)pack2bf(xv[t].z, xv[t].w) << 32) | pack2bf(xv[t].x, xv[t].y);
            *(unsigned long long*)&buf[tt][c ^ (tt << 2)] = v;
        }
    }

    // la loads (L2-resident) issued after x batches; land during barrier A + b1 reads.
    short8 la[8][2];
    #pragma unroll
    for (int pp = 0; pp < 8; ++pp) {
        const int p = w * 8 + pp;
        la[pp][0] = *(const short8*)(Lb + (size_t)((p * 2 + 0) * 64 + lane) * 8);
        la[pp][1] = *(const short8*)(Lb + (size_t)((p * 2 + 1) * 64 + lane) * 8);
    }
    block_sync();   // A: stage-in writes visible

    // ---------- stage 1 reads (batched; all waves finish before any y1 write) ----------
    short8 b1[8];
    #pragma unroll
    for (int pp = 0; pp < 8; ++pp) {
        const int p = w * 8 + pp;
        #pragma unroll
        for (int j = 0; j < 8; ++j)          // b1[j] = x[tl][m=quad*8+j][p]
            b1[pp][j] = (short)buf[tl][(quad * 256 + j * 32 + p) ^ (tl << 2)];
    }
    block_sync();   // B: all x reads done -> buffer reusable for y1

    // ---------- stage 1 MFMAs + b64 y1 writes ----------
    #pragma unroll
    for (int pp = 0; pp < 8; ++pp) {
        const int p = w * 8 + pp;
        #pragma unroll
        for (int qt = 0; qt < 2; ++qt) {
            floatx4 acc = {0.f, 0.f, 0.f, 0.f};
            acc = __builtin_amdgcn_mfma_f32_16x16x32_bf16(la[pp][qt], b1[pp], acc, 0, 0, 0);
            // lane holds y1[q = qt*16+quad*4 + 0..3][t=tl]; layout [t][p*32+q]
            // makes the 4 consecutive q one ds_write_b64.
            const unsigned long long v =
                ((unsigned long long)pack2bf(acc[2], acc[3]) << 32) | pack2bf(acc[0], acc[1]);
            const int el = p * 32 + qt * 16 + quad * 4;
            *(unsigned long long*)&buf[tl][el ^ (tl << 2)] = v;
        }
    }

    // ra issued here: la is dead (consumed above); ra lands during barrier C +
    // the 64 b2 reads (~500 cyc lead over first stage-2 MFMA).
    short8 ra[8][2];
    #pragma unroll
    for (int qq = 0; qq < 8; ++qq) {
        const int q = w * 8 + qq;
        ra[qq][0] = *(const short8*)(Rb + (size_t)((q * 2 + 0) * 64 + lane) * 8);
        ra[qq][1] = *(const short8*)(Rb + (size_t)((q * 2 + 1) * 64 + lane) * 8);
    }
    block_sync();   // C: y1 writes visible

    // ---------- stage 2 reads (batched) ----------
    short8 b2[8];
    #pragma unroll
    for (int qq = 0; qq < 8; ++qq) {
        const int q = w * 8 + qq;
        #pragma unroll
        for (int j = 0; j < 8; ++j)          // b2[j] = y1[tl][p=quad*8+j][q]
            b2[qq][j] = (short)buf[tl][((quad * 8 + j) * 32 + q) ^ (tl << 2)];
    }
    block_sync();   // D: all y1 reads done -> buffer reusable for y2

    // ---------- stage 2 MFMAs + y2 writes ----------
    #pragma unroll
    for (int qq = 0; qq < 8; ++qq) {
        const int q = w * 8 + qq;
        #pragma unroll
        for (int rt = 0; rt < 2; ++rt) {
            floatx4 z = {0.f, 0.f, 0.f, 0.f};
            const floatx4 acc =
                __builtin_amdgcn_mfma_f32_16x16x32_bf16(ra[qq][rt], b2[qq], z, 0, 0, 0);
            const unsigned int lo = pack2bf(acc[0], acc[1]);
            const unsigned int hi = pack2bf(acc[2], acc[3]);
            const int r0 = rt * 16 + quad * 4;
            buf[tl][((r0    ) * 32 + q) ^ (tl << 2)] = (unsigned short)lo;
            buf[tl][((r0 + 1) * 32 + q) ^ (tl << 2)] = (unsigned short)(lo >> 16);
            buf[tl][((r0 + 2) * 32 + q) ^ (tl << 2)] = (unsigned short)hi;
            buf[tl][((r0 + 3) * 32 + q) ^ (tl << 2)] = (unsigned short)(hi >> 16);
        }
    }
    block_sync();   // E: y2 writes visible

    // ---------- dump: buf -> out, b64 LDS reads + coalesced float4 stores ----------
    #pragma unroll
    for (int t = 0; t < 16; ++t) {
        const unsigned long long v = *(const unsigned long long*)&buf[t][c ^ (t << 2)];
        const unsigned int lo = (unsigned int)v;
        const unsigned int hi = (unsigned int)(v >> 32);
        float4 o;
        o.x = bf2f(lo & 0xffffu); o.y = bf2f(lo >> 16);
        o.z = bf2f(hi & 0xffffu); o.w = bf2f(hi >> 16);
        *(float4*)(out + (tok0 + t) * 1024 + c) = o;
    }
}

extern "C" void kernel_launch(void* const* d_in, const int* in_sizes, int n_in,
                              void* d_out, int out_size, void* d_ws, size_t ws_size,
                              hipStream_t stream) {
    const float* x = (const float*)d_in[0];   // (8, 4096, 1024) fp32
    const float* L = (const float*)d_in[1];   // (32, 32, 32) fp32
    const float* R = (const float*)d_in[2];   // (32, 32, 32) fp32
    float* out = (float*)d_out;

    unsigned short* Lb = (unsigned short*)d_ws;          // 32768 bf16 = 64 KiB
    unsigned short* Rb = Lb + 32768;                     // 32768 bf16 = 64 KiB

    prep_weights<<<32, 256, 0, stream>>>(L, R, Lb, Rb);  // L2-resident after

    const int n_tokens = 8 * 4096;
    const int grid = n_tokens / 16;                      // 2048 blocks x 16 tokens
    monarch_kernel<<<grid, 256, 0, stream>>>(x, Lb, Rb, out);
}

// Round 5
// 238.193 us; speedup vs baseline: 1.2855x; 1.2855x over previous
//
#include <hip/hip_runtime.h>
#include <hip/hip_bf16.h>

// MonarchOutProjection: out[t][r*32+q] = sum_p R[q][r][p] * sum_m L[p][q][m] * x[t][m*32+p]
// Round 7: occupancy via thread-count, not launch-bounds caps.
// Evidence r2-r6: clean variants pin at 87us, all pipes <15%, 2-3 blocks/CU resident;
// waves stalled ~85% on the load->LDS->barrier chain. Both prior TLP attempts (r3
// persistent, r6 (256,5)) died to COMPILER SPILLS under forced VGPR caps (r6: cap
// 102 -> compiler chose 48 + 203MB scratch writes).
// Fix: 512 threads/block, each of 8 waves owns 4 p/q values (was 4 waves x 8).
//  - per-wave reg demand halves by construction: la/ra 32, b1/b2 16, xv 8xfloat4.
//    NO min-waves clause -> compiler allocates freely (expect ~64-84 VGPR, no spill).
//  - occupancy: 32KB LDS -> 5 blocks; 8 waves/block -> 4 blocks = 32 waves/CU cap
//    (vs 8-12 measured in r2/r4). Per-wave chain also halves.
//  - otherwise r4 verbatim: single 32KB buffer, batched reads, 5 lgkm-only barriers
//    (never drain vmcnt), sequential la->ra residency, swizzle el ^ (t<<2).

typedef __attribute__((ext_vector_type(8))) short short8;
typedef __attribute__((ext_vector_type(4))) float floatx4;

__device__ __forceinline__ unsigned int pack2bf(float a, float b) {
    __hip_bfloat162 h = __float22bfloat162_rn(float2{a, b});  // packed cvt
    return *(unsigned int*)&h;
}
__device__ __forceinline__ float bf2f(unsigned int u16) {
    return __uint_as_float(u16 << 16);
}

// Barrier with LDS-only drain: do NOT drain vmcnt (keeps global loads in flight).
__device__ __forceinline__ void block_sync() {
    asm volatile("s_waitcnt lgkmcnt(0)" ::: "memory");
    __builtin_amdgcn_s_barrier();
    asm volatile("" ::: "memory");
}

// Lb[(p*2+qt)*64 + lane] (short8) = L[p][q=qt*16+(lane&15)][m=(lane>>4)*8 .. +8] as bf16.
// Same for Rb. 8192 threads, one short8 each. (unchanged)
__global__ void prep_weights(const float* __restrict__ L, const float* __restrict__ R,
                             unsigned short* __restrict__ Lb, unsigned short* __restrict__ Rb) {
    const int t = blockIdx.x * 256 + threadIdx.x;          // 0..8191
    const float* src        = (t < 4096) ? L : R;
    unsigned short* dst     = (t < 4096) ? Lb : Rb;
    const int i    = t & 4095;                             // (p*2+qt)*64 + lane
    const int lane = i & 63;
    const int pq   = i >> 6;
    const int p    = pq >> 1;
    const int qt   = pq & 1;
    const int q    = qt * 16 + (lane & 15);
    const int m0   = (lane >> 4) * 8;
    const float* s = src + (p * 32 + q) * 32 + m0;
    uint4 o;
    o.x = pack2bf(s[0], s[1]);
    o.y = pack2bf(s[2], s[3]);
    o.z = pack2bf(s[4], s[5]);
    o.w = pack2bf(s[6], s[7]);
    *(uint4*)(dst + (size_t)i * 8) = o;
}

__global__ __launch_bounds__(512)
void monarch_kernel(const float* __restrict__ x,
                    const unsigned short* __restrict__ Lb,
                    const unsigned short* __restrict__ Rb,
                    float* __restrict__ out) {
    // One buffer, three logical lives: x (channel layout m*32+p), y1 ([p*32+q]),
    // y2 ([r*32+q] == output channel layout). Element el of row t lives at
    // el ^ (t<<2): XOR bits 2..5 -> 16-bank spread, b64 alignment preserved.
    __shared__ __align__(16) unsigned short buf[16][1024];   // 32 KiB

    const int tid  = threadIdx.x;     // 0..511
    const int w    = tid >> 6;        // wave 0..7
    const int lane = tid & 63;
    const int tl   = lane & 15;       // token row / MFMA col
    const int quad = lane >> 4;
    const int c    = (tid & 255) * 4; // stage-in / dump channel base (0..1020)
    const int th   = (tid >> 8) * 8;  // stage-in / dump token half (0 or 8)
    const long tok0 = (long)blockIdx.x * 16;

    // ---------- phase 0: x loads (8 float4 per thread, two thread-halves) ----------
    float4 xv[8];
    #pragma unroll
    for (int t = 0; t < 8; ++t)
        xv[t] = *(const float4*)(x + (tok0 + th + t) * 1024 + c);
    #pragma unroll
    for (int t = 0; t < 8; ++t) {
        const int tt = th + t;
        const unsigned long long v =
            ((unsigned long long)pack2bf(xv[t].z, xv[t].w) << 32) | pack2bf(xv[t].x, xv[t].y);
        *(unsigned long long*)&buf[tt][c ^ (tt << 2)] = v;
    }

    // la loads (L2-resident): p = w*4 + pp. Land during barrier A + b1 reads.
    short8 la[4][2];
    #pragma unroll
    for (int pp = 0; pp < 4; ++pp) {
        const int p = w * 4 + pp;
        la[pp][0] = *(const short8*)(Lb + (size_t)((p * 2 + 0) * 64 + lane) * 8);
        la[pp][1] = *(const short8*)(Lb + (size_t)((p * 2 + 1) * 64 + lane) * 8);
    }
    block_sync();   // A: stage-in writes visible

    // ---------- stage 1 reads (batched; all waves finish before any y1 write) ----------
    short8 b1[4];
    #pragma unroll
    for (int pp = 0; pp < 4; ++pp) {
        const int p = w * 4 + pp;
        #pragma unroll
        for (int j = 0; j < 8; ++j)          // b1[j] = x[tl][m=quad*8+j][p]
            b1[pp][j] = (short)buf[tl][(quad * 256 + j * 32 + p) ^ (tl << 2)];
    }
    block_sync();   // B: all x reads done -> buffer reusable for y1

    // ---------- stage 1 MFMAs + b64 y1 writes ----------
    #pragma unroll
    for (int pp = 0; pp < 4; ++pp) {
        const int p = w * 4 + pp;
        #pragma unroll
        for (int qt = 0; qt < 2; ++qt) {
            floatx4 acc = {0.f, 0.f, 0.f, 0.f};
            acc = __builtin_amdgcn_mfma_f32_16x16x32_bf16(la[pp][qt], b1[pp], acc, 0, 0, 0);
            // lane holds y1[q = qt*16+quad*4 + 0..3][t=tl]; layout [t][p*32+q]
            // makes the 4 consecutive q one ds_write_b64.
            const unsigned long long v =
                ((unsigned long long)pack2bf(acc[2], acc[3]) << 32) | pack2bf(acc[0], acc[1]);
            const int el = p * 32 + qt * 16 + quad * 4;
            *(unsigned long long*)&buf[tl][el ^ (tl << 2)] = v;
        }
    }

    // ra issued here: la is dead; ra lands during barrier C + the b2 reads.
    short8 ra[4][2];
    #pragma unroll
    for (int qq = 0; qq < 4; ++qq) {
        const int q = w * 4 + qq;
        ra[qq][0] = *(const short8*)(Rb + (size_t)((q * 2 + 0) * 64 + lane) * 8);
        ra[qq][1] = *(const short8*)(Rb + (size_t)((q * 2 + 1) * 64 + lane) * 8);
    }
    block_sync();   // C: y1 writes visible

    // ---------- stage 2 reads (batched) ----------
    short8 b2[4];
    #pragma unroll
    for (int qq = 0; qq < 4; ++qq) {
        const int q = w * 4 + qq;
        #pragma unroll
        for (int j = 0; j < 8; ++j)          // b2[j] = y1[tl][p=quad*8+j][q]
            b2[qq][j] = (short)buf[tl][((quad * 8 + j) * 32 + q) ^ (tl << 2)];
    }
    block_sync();   // D: all y1 reads done -> buffer reusable for y2

    // ---------- stage 2 MFMAs + y2 writes ----------
    #pragma unroll
    for (int qq = 0; qq < 4; ++qq) {
        const int q = w * 4 + qq;
        #pragma unroll
        for (int rt = 0; rt < 2; ++rt) {
            floatx4 z = {0.f, 0.f, 0.f, 0.f};
            const floatx4 acc =
                __builtin_amdgcn_mfma_f32_16x16x32_bf16(ra[qq][rt], b2[qq], z, 0, 0, 0);
            const unsigned int lo = pack2bf(acc[0], acc[1]);
            const unsigned int hi = pack2bf(acc[2], acc[3]);
            const int r0 = rt * 16 + quad * 4;
            buf[tl][((r0    ) * 32 + q) ^ (tl << 2)] = (unsigned short)lo;
            buf[tl][((r0 + 1) * 32 + q) ^ (tl << 2)] = (unsigned short)(lo >> 16);
            buf[tl][((r0 + 2) * 32 + q) ^ (tl << 2)] = (unsigned short)hi;
            buf[tl][((r0 + 3) * 32 + q) ^ (tl << 2)] = (unsigned short)(hi >> 16);
        }
    }
    block_sync();   // E: y2 writes visible

    // ---------- dump: buf -> out, b64 LDS reads + coalesced float4 stores ----------
    #pragma unroll
    for (int t = 0; t < 8; ++t) {
        const int tt = th + t;
        const unsigned long long v = *(const unsigned long long*)&buf[tt][c ^ (tt << 2)];
        const unsigned int lo = (unsigned int)v;
        const unsigned int hi = (unsigned int)(v >> 32);
        float4 o;
        o.x = bf2f(lo & 0xffffu); o.y = bf2f(lo >> 16);
        o.z = bf2f(hi & 0xffffu); o.w = bf2f(hi >> 16);
        *(float4*)(out + (tok0 + tt) * 1024 + c) = o;
    }
}

extern "C" void kernel_launch(void* const* d_in, const int* in_sizes, int n_in,
                              void* d_out, int out_size, void* d_ws, size_t ws_size,
                              hipStream_t stream) {
    const float* x = (const float*)d_in[0];   // (8, 4096, 1024) fp32
    const float* L = (const float*)d_in[1];   // (32, 32, 32) fp32
    const float* R = (const float*)d_in[2];   // (32, 32, 32) fp32
    float* out = (float*)d_out;

    unsigned short* Lb = (unsigned short*)d_ws;          // 32768 bf16 = 64 KiB
    unsigned short* Rb = Lb + 32768;                     // 32768 bf16 = 64 KiB

    prep_weights<<<32, 256, 0, stream>>>(L, R, Lb, Rb);  // L2-resident after

    const int n_tokens = 8 * 4096;
    const int grid = n_tokens / 16;                      // 2048 blocks x 16 tokens
    monarch_kernel<<<grid, 512, 0, stream>>>(x, Lb, Rb, out);
}